// Round 10
// baseline (310.884 us; speedup 1.0000x reference)
//
#include <hip/hip_runtime.h>
#include <math.h>

#define N_NODES 50000
#define N_EDGES 800000
#define IN_DIM 128
#define OUT_DIM 16
#define N_HEADS 4
#define HID 64            // N_HEADS*OUT_DIM
#define AW_COLS 33        // 2*OUT_DIM+1
#define NBLK ((N_NODES + 255) / 256)   // 196

// h = nodes @ W.T + b, LDS-free. Lane = node (64 nodes/block), wave = one head's
// 16 outputs. nodes quads: per-lane global b128 (L1-resident, reused x16 outputs);
// W quads: wave-uniform address -> scalar s_load path. f64 accumulate, k-ascending
// (bit-identical h to R9). Alphas epilogue fully in-lane (lane owns its head's 16
// h values). No LDS, no barriers.
// NOTE (R7/R8 post-mortem): v_mfma_f64_16x16x4_f64 produced deterministic wrong h
// (identical absmax across two stagings) — f64 MFMA lane mapping differs from the
// f32-verified convention. Do not re-attempt without a hardware layout probe.
__global__ __launch_bounds__(256) void gemm_h(const float* __restrict__ nodes,
                                              const float* __restrict__ W,
                                              const float* __restrict__ b,
                                              const float* __restrict__ attn_W,
                                              float* __restrict__ h,
                                              double* __restrict__ a_src,
                                              double* __restrict__ a_dst) {
    int wv = threadIdx.x >> 6;            // head / o-range selector (wave-uniform)
    int lane = threadIdx.x & 63;
    int n = blockIdx.x * 64 + lane;
    bool valid = n < N_NODES;
    const float* nrow = nodes + (long long)n * IN_DIM;
    int obase = wv * 16;
    double acc[16];
    #pragma unroll
    for (int i = 0; i < 16; ++i) acc[i] = (double)b[obase + i];
    for (int kq = 0; kq < 32; ++kq) {
        float4 nv = valid ? *(const float4*)(nrow + 4 * kq)
                          : make_float4(0.f, 0.f, 0.f, 0.f);
        #pragma unroll
        for (int i = 0; i < 16; ++i) {
            // wave-uniform address -> scalar load path
            float4 wq = *(const float4*)(W + (long long)(obase + i) * IN_DIM + 4 * kq);
            acc[i] += (double)wq.x * (double)nv.x;
            acc[i] += (double)wq.y * (double)nv.y;
            acc[i] += (double)wq.z * (double)nv.z;
            acc[i] += (double)wq.w * (double)nv.w;
        }
    }
    if (!valid) return;
    float hf[16];
    #pragma unroll
    for (int i = 0; i < 16; ++i) hf[i] = (float)acc[i];
    float* hp = h + (long long)n * HID + obase;
    #pragma unroll
    for (int i = 0; i < 4; ++i)
        *(float4*)(hp + 4 * i) = make_float4(hf[4 * i], hf[4 * i + 1],
                                             hf[4 * i + 2], hf[4 * i + 3]);
    // alphas for head = wv, entirely in-lane (fp64, d ascending)
    double c0 = 0.0, c1 = 0.0;
    #pragma unroll
    for (int d = 0; d < OUT_DIM; ++d) {
        c0 += (double)hf[d] * (double)attn_W[wv * AW_COLS + d];
        c1 += (double)hf[d] * (double)attn_W[wv * AW_COLS + OUT_DIM + d];
    }
    a_src[n * N_HEADS + wv] = c0;
    a_dst[n * N_HEADS + wv] = c1;
}

// Receiver histogram + block-reduced double sum of edges[sender] -> Ssum.
__global__ __launch_bounds__(256) void hist(const int* __restrict__ senders,
                                            const int* __restrict__ receivers,
                                            const float* __restrict__ edges,
                                            int* __restrict__ counts,
                                            double* __restrict__ Ssum) {
    __shared__ double red[256];
    int t = threadIdx.x;
    int e = blockIdx.x * 256 + t;
    double sp = 0.0;
    if (e < N_EDGES) {
        atomicAdd(&counts[receivers[e]], 1);
        sp = (double)edges[senders[e]];
    }
    red[t] = sp;
    __syncthreads();
    for (int off = 128; off > 0; off >>= 1) {
        if (t < off) red[t] += red[t + off];
        __syncthreads();
    }
    if (t == 0) atomicAdd(Ssum, red[0]);
}

// ---- 3-phase multi-block exclusive scan of counts -> offsets/cursor ----
__global__ __launch_bounds__(256) void partial_sums(const int* __restrict__ counts,
                                                    int* __restrict__ partials) {
    __shared__ int red[256];
    int t = threadIdx.x;
    int i = blockIdx.x * 256 + t;
    red[t] = (i < N_NODES) ? counts[i] : 0;
    __syncthreads();
    for (int off = 128; off > 0; off >>= 1) {
        if (t < off) red[t] += red[t + off];
        __syncthreads();
    }
    if (t == 0) partials[blockIdx.x] = red[0];
}

__global__ __launch_bounds__(256) void scan_partials(int* __restrict__ partials) {
    __shared__ int s[256];
    int t = threadIdx.x;
    int v = (t < NBLK) ? partials[t] : 0;
    s[t] = v;
    __syncthreads();
    for (int off = 1; off < 256; off <<= 1) {
        int u = (t >= off) ? s[t - off] : 0;
        __syncthreads();
        s[t] += u;
        __syncthreads();
    }
    if (t < NBLK) partials[t] = s[t] - v;   // exclusive block offsets
}

__global__ __launch_bounds__(256) void scan_final(const int* __restrict__ counts,
                                                  const int* __restrict__ partials,
                                                  int* __restrict__ offsets,
                                                  int* __restrict__ cursor) {
    __shared__ int s[256];
    int t = threadIdx.x;
    int i = blockIdx.x * 256 + t;
    int c = (i < N_NODES) ? counts[i] : 0;
    s[t] = c;
    __syncthreads();
    for (int off = 1; off < 256; off <<= 1) {
        int u = (t >= off) ? s[t - off] : 0;
        __syncthreads();
        s[t] += u;
        __syncthreads();
    }
    if (i < N_NODES) {
        int pos = partials[blockIdx.x] + s[t] - c;   // exclusive prefix
        offsets[i] = pos;
        cursor[i] = pos;
    }
    if (i == 0) offsets[N_NODES] = N_EDGES;
}

// Scatter sender ids into receiver-sorted order.
__global__ __launch_bounds__(256) void fill_srt(const int* __restrict__ senders,
                                                const int* __restrict__ receivers,
                                                int* __restrict__ cursor,
                                                int* __restrict__ srt_sender) {
    int e = blockIdx.x * 256 + threadIdx.x;
    if (e >= N_EDGES) return;
    int pos = atomicAdd(&cursor[receivers[e]], 1);
    srt_sender[pos] = senders[e];
}

// One wave per node. Lane = (head hd=lane>>4, slot q=lane&15); lane evaluates
// edges q+16j for ITS head only. Segmented 16-lane reductions for max/den.
// Near-one-hot softmax -> ballot-compressed accumulate loop.
__global__ __launch_bounds__(256) void node_fused(
    const float* __restrict__ h, const double* __restrict__ a_src,
    const double* __restrict__ a_dst, const float* __restrict__ edges,
    const int* __restrict__ srt_sender, const int* __restrict__ offsets,
    const float* __restrict__ attn_W, const float* __restrict__ attn_b,
    const double* __restrict__ Ssum, float* __restrict__ out) {
    int node = blockIdx.x * 4 + (threadIdx.x >> 6);
    int lane = threadIdx.x & 63;
    if (node >= N_NODES) return;
    int hd = lane >> 4, q = lane & 15;
    int start = offsets[node], end = offsets[node + 1];
    long long obase = (long long)node * HID + lane;
    if (start >= end) { out[obase] = 0.f; return; }

    double S = 4.0 * Ssum[0];                       // sent_e tiled over heads
    double w    = (double)attn_W[hd * AW_COLS + 2 * OUT_DIM];
    double bb   = (double)attn_b[hd];
    double adst = a_dst[node * N_HEADS + hd];
    float m_run = -INFINITY;
    float den = 0.f, acc = 0.f;

    for (int cbase = start; cbase < end; cbase += 64) {
        int cd = end - cbase; if (cd > 64) cd = 64;
        float y[4], ev[4];
        #pragma unroll
        for (int j = 0; j < 4; ++j) {
            int ei = q + 16 * j;
            y[j] = -INFINITY;
            if (ei < cd) {
                int s = srt_sender[cbase + ei];
                double se = (double)edges[s];
                double as = a_src[(long long)s * N_HEADS + hd];
                double yy = as + adst + se * w + bb;
                yy = yy > 0.0 ? yy : 0.01 * yy;     // leaky (fp64, then round)
                y[j] = (float)yy;
            }
        }
        // per-head (16-lane segment) chunk max
        float mv = fmaxf(fmaxf(y[0], y[1]), fmaxf(y[2], y[3]));
        #pragma unroll
        for (int k = 1; k <= 8; k <<= 1)
            mv = fmaxf(mv, __shfl_xor(mv, k, 64));
        float mn = fmaxf(m_run, mv);
        float sc = (m_run == -INFINITY) ? 0.f
                 : __expf((float)(S * ((double)m_run - (double)mn)));
        den *= sc; acc *= sc; m_run = mn;
        // ev per slot (fp64 arg, fp32 exp) + segmented den sum
        float dsum = 0.f;
        #pragma unroll
        for (int j = 0; j < 4; ++j) {
            ev[j] = (y[j] == -INFINITY) ? 0.f
                  : __expf((float)(S * ((double)y[j] - (double)m_run)));
            dsum += ev[j];
        }
        #pragma unroll
        for (int k = 1; k <= 8; k <<= 1)
            dsum += __shfl_xor(dsum, k, 64);
        den += dsum;
        // accumulate only surviving edges (exact skip of ev==0)
        #pragma unroll
        for (int j = 0; j < 4; ++j) {
            unsigned long long mk = __ballot(ev[j] != 0.f);
            unsigned um = (unsigned)((mk | (mk >> 16) | (mk >> 32) | (mk >> 48)) & 0xFFFFull);
            while (um) {
                int qq = __builtin_ctz(um);
                um &= um - 1;
                float evv = __shfl(ev[j], (lane & 48) | qq, 64);  // own head's ev
                int sj = srt_sender[cbase + 16 * j + qq];         // uniform -> scalar
                if (evv != 0.f)
                    acc = fmaf(evv, h[(long long)sj * HID + lane], acc);
            }
        }
    }
    float r = (den > 0.f) ? acc / den : 0.f;
    out[obase] = r > 0.f ? r : 0.01f * r;
}

static inline char* ws_take(char*& p, size_t bytes) {
    char* cur = p;
    p += (bytes + 255) & ~(size_t)255;   // keep every buffer 256B-aligned
    return cur;
}

extern "C" void kernel_launch(void* const* d_in, const int* in_sizes, int n_in,
                              void* d_out, int out_size, void* d_ws, size_t ws_size,
                              hipStream_t stream) {
    const float* nodes     = (const float*)d_in[0];
    const float* edges     = (const float*)d_in[1];
    const int*   senders   = (const int*)d_in[2];
    const int*   receivers = (const int*)d_in[3];
    const float* W         = (const float*)d_in[4];
    const float* b         = (const float*)d_in[5];
    const float* attn_W    = (const float*)d_in[6];
    const float* attn_b    = (const float*)d_in[7];
    float* out = (float*)d_out;

    char* p = (char*)d_ws;
    float*  h          = (float*)ws_take(p, sizeof(float) * N_NODES * HID);
    double* a_src      = (double*)ws_take(p, sizeof(double) * N_NODES * N_HEADS);
    double* a_dst      = (double*)ws_take(p, sizeof(double) * N_NODES * N_HEADS);
    int*    counts     = (int*)ws_take(p, sizeof(int) * N_NODES);
    int*    offsets    = (int*)ws_take(p, sizeof(int) * (N_NODES + 1));
    int*    cursor     = (int*)ws_take(p, sizeof(int) * N_NODES);
    int*    partials   = (int*)ws_take(p, sizeof(int) * NBLK);
    int*    srt_sender = (int*)ws_take(p, sizeof(int) * (size_t)N_EDGES);
    double* Ssum       = (double*)ws_take(p, sizeof(double));

    hipMemsetAsync(counts, 0, sizeof(int) * N_NODES, stream);
    hipMemsetAsync(Ssum, 0, sizeof(double), stream);

    gemm_h<<<(N_NODES + 63) / 64, 256, 0, stream>>>(nodes, W, b, attn_W, h, a_src, a_dst);
    hist<<<(N_EDGES + 255) / 256, 256, 0, stream>>>(senders, receivers, edges, counts, Ssum);
    partial_sums<<<NBLK, 256, 0, stream>>>(counts, partials);
    scan_partials<<<1, 256, 0, stream>>>(partials);
    scan_final<<<NBLK, 256, 0, stream>>>(counts, partials, offsets, cursor);
    fill_srt<<<(N_EDGES + 255) / 256, 256, 0, stream>>>(senders, receivers, cursor, srt_sender);
    node_fused<<<(N_NODES + 3) / 4, 256, 0, stream>>>(
        h, a_src, a_dst, edges, srt_sender, offsets, attn_W, attn_b, Ssum, out);
}

// Round 11
// 283.685 us; speedup vs baseline: 1.0959x; 1.0959x over previous
//
#include <hip/hip_runtime.h>
#include <math.h>

#define N_NODES 50000
#define N_EDGES 800000
#define IN_DIM 128
#define OUT_DIM 16
#define N_HEADS 4
#define HID 64            // N_HEADS*OUT_DIM
#define AW_COLS 33        // 2*OUT_DIM+1
#define NBLK ((N_NODES + 255) / 256)   // 196
#define GN 32             // nodes per block (gemm)
#define GW 8              // nodes per wave  (gemm)

// h = nodes @ W.T + b (fp64 accumulate, bit-identical op order to the R6/R9
// verified kernel) + fused alphas epilogue. Block = 256 = 4 waves; block tile =
// 32 nodes; wave = 8 nodes, lane = output element. Per kq the wave reads its W
// quad ONCE (shared across 8 nodes) and broadcasts 8 node quads from LDS —
// amortizes W staging 8x and wv-reads/cvts 8x vs R6's 4-nodes-per-block.
// sW uses the per-row quad rotation so ds_read_b128 spreads bank-quads.
// NOTE (R7/R8): v_mfma_f64_16x16x4_f64 gave deterministic wrong h (f64 MFMA
// lane mapping differs from the f32-verified convention) — shelved.
// NOTE (R10): "wave-uniform address -> s_load" does NOT happen when the address
// derives from threadIdx (divergence analysis); global-W reads were latency-bound.
__global__ __launch_bounds__(256) void gemm_h(const float* __restrict__ nodes,
                                              const float* __restrict__ W,
                                              const float* __restrict__ b,
                                              const float* __restrict__ attn_W,
                                              float* __restrict__ h,
                                              double* __restrict__ a_src,
                                              double* __restrict__ a_dst) {
    __shared__ float sW[HID * IN_DIM];     // 32 KB, rotated-quad layout
    __shared__ float sN[GN * IN_DIM];      // 16 KB
    int t = threadIdx.x;
    for (int i4 = t; i4 < HID * IN_DIM / 4; i4 += 256) {
        int o = i4 >> 5, kq = i4 & 31;
        float4 v = ((const float4*)W)[i4];
        *(float4*)&sW[o * IN_DIM + (((kq + o) & 31) << 2)] = v;
    }
    int node0 = blockIdx.x * GN;
    for (int i4 = t; i4 < GN * IN_DIM / 4; i4 += 256) {
        int ln = i4 >> 5;
        int n = node0 + ln;
        float4 v = (n < N_NODES) ? ((const float4*)nodes)[(long long)n * (IN_DIM / 4) + (i4 & 31)]
                                 : make_float4(0.f, 0.f, 0.f, 0.f);
        *(float4*)&sN[i4 << 2] = v;
    }
    __syncthreads();
    int w = t >> 6, o = t & 63;
    double acc[GW];
    #pragma unroll
    for (int j = 0; j < GW; ++j) acc[j] = (double)b[o];
    const float* wrow = &sW[o * IN_DIM];
    const float* nbase = &sN[(w * GW) * IN_DIM];
    for (int kq = 0; kq < 32; ++kq) {
        float4 wv = *(const float4*)&wrow[((kq + o) & 31) << 2];   // rotated, spread banks
        double wx = (double)wv.x, wy = (double)wv.y;
        double wz = (double)wv.z, ww = (double)wv.w;
        #pragma unroll
        for (int j = 0; j < GW; ++j) {
            float4 nv = *(const float4*)&nbase[j * IN_DIM + (kq << 2)];  // broadcast
            acc[j] += wx * (double)nv.x;
            acc[j] += wy * (double)nv.y;
            acc[j] += wz * (double)nv.z;
            acc[j] += ww * (double)nv.w;
        }
    }
    // epilogue: h write + alphas (bit-identical order to R6/R9)
    int hd = o >> 4, d = o & 15;
    double aw0 = (double)attn_W[hd * AW_COLS + d];
    double aw1 = (double)attn_W[hd * AW_COLS + OUT_DIM + d];
    #pragma unroll
    for (int j = 0; j < GW; ++j) {
        int n = node0 + w * GW + j;          // wave-uniform validity
        if (n >= N_NODES) break;
        float hf = (float)acc[j];
        h[(long long)n * HID + o] = hf;
        double c0 = (double)hf * aw0;
        double c1 = (double)hf * aw1;
        #pragma unroll
        for (int k = 1; k <= 8; k <<= 1) {
            c0 += __shfl_xor(c0, k, 64);
            c1 += __shfl_xor(c1, k, 64);
        }
        if (d == 0) {
            a_src[n * N_HEADS + hd] = c0;
            a_dst[n * N_HEADS + hd] = c1;
        }
    }
}

// Receiver histogram + block-reduced double sum of edges[sender] -> Ssum.
__global__ __launch_bounds__(256) void hist(const int* __restrict__ senders,
                                            const int* __restrict__ receivers,
                                            const float* __restrict__ edges,
                                            int* __restrict__ counts,
                                            double* __restrict__ Ssum) {
    __shared__ double red[256];
    int t = threadIdx.x;
    int e = blockIdx.x * 256 + t;
    double sp = 0.0;
    if (e < N_EDGES) {
        atomicAdd(&counts[receivers[e]], 1);
        sp = (double)edges[senders[e]];
    }
    red[t] = sp;
    __syncthreads();
    for (int off = 128; off > 0; off >>= 1) {
        if (t < off) red[t] += red[t + off];
        __syncthreads();
    }
    if (t == 0) atomicAdd(Ssum, red[0]);
}

// ---- 3-phase multi-block exclusive scan of counts -> offsets/cursor ----
__global__ __launch_bounds__(256) void partial_sums(const int* __restrict__ counts,
                                                    int* __restrict__ partials) {
    __shared__ int red[256];
    int t = threadIdx.x;
    int i = blockIdx.x * 256 + t;
    red[t] = (i < N_NODES) ? counts[i] : 0;
    __syncthreads();
    for (int off = 128; off > 0; off >>= 1) {
        if (t < off) red[t] += red[t + off];
        __syncthreads();
    }
    if (t == 0) partials[blockIdx.x] = red[0];
}

__global__ __launch_bounds__(256) void scan_partials(int* __restrict__ partials) {
    __shared__ int s[256];
    int t = threadIdx.x;
    int v = (t < NBLK) ? partials[t] : 0;
    s[t] = v;
    __syncthreads();
    for (int off = 1; off < 256; off <<= 1) {
        int u = (t >= off) ? s[t - off] : 0;
        __syncthreads();
        s[t] += u;
        __syncthreads();
    }
    if (t < NBLK) partials[t] = s[t] - v;   // exclusive block offsets
}

__global__ __launch_bounds__(256) void scan_final(const int* __restrict__ counts,
                                                  const int* __restrict__ partials,
                                                  int* __restrict__ offsets,
                                                  int* __restrict__ cursor) {
    __shared__ int s[256];
    int t = threadIdx.x;
    int i = blockIdx.x * 256 + t;
    int c = (i < N_NODES) ? counts[i] : 0;
    s[t] = c;
    __syncthreads();
    for (int off = 1; off < 256; off <<= 1) {
        int u = (t >= off) ? s[t - off] : 0;
        __syncthreads();
        s[t] += u;
        __syncthreads();
    }
    if (i < N_NODES) {
        int pos = partials[blockIdx.x] + s[t] - c;   // exclusive prefix
        offsets[i] = pos;
        cursor[i] = pos;
    }
    if (i == 0) offsets[N_NODES] = N_EDGES;
}

// Scatter sender ids into receiver-sorted order.
__global__ __launch_bounds__(256) void fill_srt(const int* __restrict__ senders,
                                                const int* __restrict__ receivers,
                                                int* __restrict__ cursor,
                                                int* __restrict__ srt_sender) {
    int e = blockIdx.x * 256 + threadIdx.x;
    if (e >= N_EDGES) return;
    int pos = atomicAdd(&cursor[receivers[e]], 1);
    srt_sender[pos] = senders[e];
}

// One wave per node. Lane = (head hd=lane>>4, slot q=lane&15); lane evaluates
// edges q+16j for ITS head only. Segmented 16-lane reductions for max/den.
// Near-one-hot softmax -> ballot-compressed accumulate loop.
__global__ __launch_bounds__(256) void node_fused(
    const float* __restrict__ h, const double* __restrict__ a_src,
    const double* __restrict__ a_dst, const float* __restrict__ edges,
    const int* __restrict__ srt_sender, const int* __restrict__ offsets,
    const float* __restrict__ attn_W, const float* __restrict__ attn_b,
    const double* __restrict__ Ssum, float* __restrict__ out) {
    int node = blockIdx.x * 4 + (threadIdx.x >> 6);
    int lane = threadIdx.x & 63;
    if (node >= N_NODES) return;
    int hd = lane >> 4, q = lane & 15;
    int start = offsets[node], end = offsets[node + 1];
    long long obase = (long long)node * HID + lane;
    if (start >= end) { out[obase] = 0.f; return; }

    double S = 4.0 * Ssum[0];                       // sent_e tiled over heads
    double w    = (double)attn_W[hd * AW_COLS + 2 * OUT_DIM];
    double bb   = (double)attn_b[hd];
    double adst = a_dst[node * N_HEADS + hd];
    float m_run = -INFINITY;
    float den = 0.f, acc = 0.f;

    for (int cbase = start; cbase < end; cbase += 64) {
        int cd = end - cbase; if (cd > 64) cd = 64;
        float y[4], ev[4];
        #pragma unroll
        for (int j = 0; j < 4; ++j) {
            int ei = q + 16 * j;
            y[j] = -INFINITY;
            if (ei < cd) {
                int s = srt_sender[cbase + ei];
                double se = (double)edges[s];
                double as = a_src[(long long)s * N_HEADS + hd];
                double yy = as + adst + se * w + bb;
                yy = yy > 0.0 ? yy : 0.01 * yy;     // leaky (fp64, then round)
                y[j] = (float)yy;
            }
        }
        // per-head (16-lane segment) chunk max
        float mv = fmaxf(fmaxf(y[0], y[1]), fmaxf(y[2], y[3]));
        #pragma unroll
        for (int k = 1; k <= 8; k <<= 1)
            mv = fmaxf(mv, __shfl_xor(mv, k, 64));
        float mn = fmaxf(m_run, mv);
        float sc = (m_run == -INFINITY) ? 0.f
                 : __expf((float)(S * ((double)m_run - (double)mn)));
        den *= sc; acc *= sc; m_run = mn;
        // ev per slot (fp64 arg, fp32 exp) + segmented den sum
        float dsum = 0.f;
        #pragma unroll
        for (int j = 0; j < 4; ++j) {
            ev[j] = (y[j] == -INFINITY) ? 0.f
                  : __expf((float)(S * ((double)y[j] - (double)m_run)));
            dsum += ev[j];
        }
        #pragma unroll
        for (int k = 1; k <= 8; k <<= 1)
            dsum += __shfl_xor(dsum, k, 64);
        den += dsum;
        // accumulate only surviving edges (exact skip of ev==0)
        #pragma unroll
        for (int j = 0; j < 4; ++j) {
            unsigned long long mk = __ballot(ev[j] != 0.f);
            unsigned um = (unsigned)((mk | (mk >> 16) | (mk >> 32) | (mk >> 48)) & 0xFFFFull);
            while (um) {
                int qq = __builtin_ctz(um);
                um &= um - 1;
                float evv = __shfl(ev[j], (lane & 48) | qq, 64);  // own head's ev
                int sj = srt_sender[cbase + 16 * j + qq];         // uniform -> scalar
                if (evv != 0.f)
                    acc = fmaf(evv, h[(long long)sj * HID + lane], acc);
            }
        }
    }
    float r = (den > 0.f) ? acc / den : 0.f;
    out[obase] = r > 0.f ? r : 0.01f * r;
}

static inline char* ws_take(char*& p, size_t bytes) {
    char* cur = p;
    p += (bytes + 255) & ~(size_t)255;   // keep every buffer 256B-aligned
    return cur;
}

extern "C" void kernel_launch(void* const* d_in, const int* in_sizes, int n_in,
                              void* d_out, int out_size, void* d_ws, size_t ws_size,
                              hipStream_t stream) {
    const float* nodes     = (const float*)d_in[0];
    const float* edges     = (const float*)d_in[1];
    const int*   senders   = (const int*)d_in[2];
    const int*   receivers = (const int*)d_in[3];
    const float* W         = (const float*)d_in[4];
    const float* b         = (const float*)d_in[5];
    const float* attn_W    = (const float*)d_in[6];
    const float* attn_b    = (const float*)d_in[7];
    float* out = (float*)d_out;

    char* p = (char*)d_ws;
    float*  h          = (float*)ws_take(p, sizeof(float) * N_NODES * HID);
    double* a_src      = (double*)ws_take(p, sizeof(double) * N_NODES * N_HEADS);
    double* a_dst      = (double*)ws_take(p, sizeof(double) * N_NODES * N_HEADS);
    int*    counts     = (int*)ws_take(p, sizeof(int) * N_NODES);
    int*    offsets    = (int*)ws_take(p, sizeof(int) * (N_NODES + 1));
    int*    cursor     = (int*)ws_take(p, sizeof(int) * N_NODES);
    int*    partials   = (int*)ws_take(p, sizeof(int) * NBLK);
    int*    srt_sender = (int*)ws_take(p, sizeof(int) * (size_t)N_EDGES);
    double* Ssum       = (double*)ws_take(p, sizeof(double));

    hipMemsetAsync(counts, 0, sizeof(int) * N_NODES, stream);
    hipMemsetAsync(Ssum, 0, sizeof(double), stream);

    gemm_h<<<(N_NODES + GN - 1) / GN, 256, 0, stream>>>(nodes, W, b, attn_W, h, a_src, a_dst);
    hist<<<(N_EDGES + 255) / 256, 256, 0, stream>>>(senders, receivers, edges, counts, Ssum);
    partial_sums<<<NBLK, 256, 0, stream>>>(counts, partials);
    scan_partials<<<1, 256, 0, stream>>>(partials);
    scan_final<<<NBLK, 256, 0, stream>>>(counts, partials, offsets, cursor);
    fill_srt<<<(N_EDGES + 255) / 256, 256, 0, stream>>>(senders, receivers, cursor, srt_sender);
    node_fused<<<(N_NODES + 3) / 4, 256, 0, stream>>>(
        h, a_src, a_dst, edges, srt_sender, offsets, attn_W, attn_b, Ssum, out);
}

// Round 12
// 269.332 us; speedup vs baseline: 1.1543x; 1.0533x over previous
//
#include <hip/hip_runtime.h>
#include <math.h>

#define N_NODES 50000
#define N_EDGES 800000
#define IN_DIM 128
#define OUT_DIM 16
#define N_HEADS 4
#define HID 64            // N_HEADS*OUT_DIM
#define AW_COLS 33        // 2*OUT_DIM+1
#define NBLK ((N_NODES + 255) / 256)   // 196
#define GN 32             // nodes per block (gemm)
#define GW 8              // nodes per wave  (gemm)
#define HE 16             // edges per thread (hist)
#define HBLK ((N_EDGES + 256 * HE - 1) / (256 * HE))   // 196
#define FE 4              // edges per thread (fill_srt)
#define FBLK ((N_EDGES + 256 * FE - 1) / (256 * FE))   // 782

// h = nodes @ W.T + b (fp64 accumulate, bit-identical op order to R6/R9/R11)
// + fused alphas epilogue. Block = 256 = 4 waves; wave = 8 nodes, lane = out elem.
// NOTE (R7/R8): v_mfma_f64_16x16x4_f64 gave deterministic wrong h — shelved.
// NOTE (R10): threadIdx-derived addresses never take the s_load path.
__global__ __launch_bounds__(256) void gemm_h(const float* __restrict__ nodes,
                                              const float* __restrict__ W,
                                              const float* __restrict__ b,
                                              const float* __restrict__ attn_W,
                                              float* __restrict__ h,
                                              double* __restrict__ a_src,
                                              double* __restrict__ a_dst) {
    __shared__ float sW[HID * IN_DIM];     // 32 KB, rotated-quad layout
    __shared__ float sN[GN * IN_DIM];      // 16 KB
    int t = threadIdx.x;
    for (int i4 = t; i4 < HID * IN_DIM / 4; i4 += 256) {
        int o = i4 >> 5, kq = i4 & 31;
        float4 v = ((const float4*)W)[i4];
        *(float4*)&sW[o * IN_DIM + (((kq + o) & 31) << 2)] = v;
    }
    int node0 = blockIdx.x * GN;
    for (int i4 = t; i4 < GN * IN_DIM / 4; i4 += 256) {
        int ln = i4 >> 5;
        int n = node0 + ln;
        float4 v = (n < N_NODES) ? ((const float4*)nodes)[(long long)n * (IN_DIM / 4) + (i4 & 31)]
                                 : make_float4(0.f, 0.f, 0.f, 0.f);
        *(float4*)&sN[i4 << 2] = v;
    }
    __syncthreads();
    int w = t >> 6, o = t & 63;
    double acc[GW];
    #pragma unroll
    for (int j = 0; j < GW; ++j) acc[j] = (double)b[o];
    const float* wrow = &sW[o * IN_DIM];
    const float* nbase = &sN[(w * GW) * IN_DIM];
    for (int kq = 0; kq < 32; ++kq) {
        float4 wv = *(const float4*)&wrow[((kq + o) & 31) << 2];   // rotated, spread banks
        double wx = (double)wv.x, wy = (double)wv.y;
        double wz = (double)wv.z, ww = (double)wv.w;
        #pragma unroll
        for (int j = 0; j < GW; ++j) {
            float4 nv = *(const float4*)&nbase[j * IN_DIM + (kq << 2)];  // broadcast
            acc[j] += wx * (double)nv.x;
            acc[j] += wy * (double)nv.y;
            acc[j] += wz * (double)nv.z;
            acc[j] += ww * (double)nv.w;
        }
    }
    int hd = o >> 4, d = o & 15;
    double aw0 = (double)attn_W[hd * AW_COLS + d];
    double aw1 = (double)attn_W[hd * AW_COLS + OUT_DIM + d];
    #pragma unroll
    for (int j = 0; j < GW; ++j) {
        int n = node0 + w * GW + j;          // wave-uniform validity
        if (n >= N_NODES) break;
        float hf = (float)acc[j];
        h[(long long)n * HID + o] = hf;
        double c0 = (double)hf * aw0;
        double c1 = (double)hf * aw1;
        #pragma unroll
        for (int k = 1; k <= 8; k <<= 1) {
            c0 += __shfl_xor(c0, k, 64);
            c1 += __shfl_xor(c1, k, 64);
        }
        if (d == 0) {
            a_src[n * N_HEADS + hd] = c0;
            a_dst[n * N_HEADS + hd] = c1;
        }
    }
}

// Receiver histogram + Ssum. Grid-stride: HE edges/thread (lane-stride-256 keeps
// every iteration coalesced), register-accumulated sp, ONE LDS reduction per
// block (R11's 1-edge/thread version did 3125 block reductions -> 59 us).
__global__ __launch_bounds__(256) void hist(const int* __restrict__ senders,
                                            const int* __restrict__ receivers,
                                            const float* __restrict__ edges,
                                            int* __restrict__ counts,
                                            double* __restrict__ Ssum) {
    __shared__ double red[256];
    int t = threadIdx.x;
    int base = blockIdx.x * 256 * HE + t;
    double sp = 0.0;
    #pragma unroll
    for (int j = 0; j < HE; ++j) {
        int e = base + j * 256;
        if (e < N_EDGES) {
            atomicAdd(&counts[receivers[e]], 1);
            sp += (double)edges[senders[e]];
        }
    }
    red[t] = sp;
    __syncthreads();
    for (int off = 128; off > 0; off >>= 1) {
        if (t < off) red[t] += red[t + off];
        __syncthreads();
    }
    if (t == 0) atomicAdd(Ssum, red[0]);
}

// ---- 3-phase multi-block exclusive scan of counts -> offsets/cursor ----
__global__ __launch_bounds__(256) void partial_sums(const int* __restrict__ counts,
                                                    int* __restrict__ partials) {
    __shared__ int red[256];
    int t = threadIdx.x;
    int i = blockIdx.x * 256 + t;
    red[t] = (i < N_NODES) ? counts[i] : 0;
    __syncthreads();
    for (int off = 128; off > 0; off >>= 1) {
        if (t < off) red[t] += red[t + off];
        __syncthreads();
    }
    if (t == 0) partials[blockIdx.x] = red[0];
}

__global__ __launch_bounds__(256) void scan_partials(int* __restrict__ partials) {
    __shared__ int s[256];
    int t = threadIdx.x;
    int v = (t < NBLK) ? partials[t] : 0;
    s[t] = v;
    __syncthreads();
    for (int off = 1; off < 256; off <<= 1) {
        int u = (t >= off) ? s[t - off] : 0;
        __syncthreads();
        s[t] += u;
        __syncthreads();
    }
    if (t < NBLK) partials[t] = s[t] - v;   // exclusive block offsets
}

__global__ __launch_bounds__(256) void scan_final(const int* __restrict__ counts,
                                                  const int* __restrict__ partials,
                                                  int* __restrict__ offsets,
                                                  int* __restrict__ cursor) {
    __shared__ int s[256];
    int t = threadIdx.x;
    int i = blockIdx.x * 256 + t;
    int c = (i < N_NODES) ? counts[i] : 0;
    s[t] = c;
    __syncthreads();
    for (int off = 1; off < 256; off <<= 1) {
        int u = (t >= off) ? s[t - off] : 0;
        __syncthreads();
        s[t] += u;
        __syncthreads();
    }
    if (i < N_NODES) {
        int pos = partials[blockIdx.x] + s[t] - c;   // exclusive prefix
        offsets[i] = pos;
        cursor[i] = pos;
    }
    if (i == 0) offsets[N_NODES] = N_EDGES;
}

// Scatter sender ids into receiver-sorted order. FE edges/thread: 4 independent
// atomic+scatter chains per thread hide the atomic round-trip latency.
__global__ __launch_bounds__(256) void fill_srt(const int* __restrict__ senders,
                                                const int* __restrict__ receivers,
                                                int* __restrict__ cursor,
                                                int* __restrict__ srt_sender) {
    int base = blockIdx.x * 256 * FE + threadIdx.x;
    #pragma unroll
    for (int j = 0; j < FE; ++j) {
        int e = base + j * 256;
        if (e < N_EDGES) {
            int pos = atomicAdd(&cursor[receivers[e]], 1);
            srt_sender[pos] = senders[e];
        }
    }
}

// One wave per node. Lane = (head hd=lane>>4, slot q=lane&15); lane evaluates
// edges q+16j for ITS head only. Segmented 16-lane reductions for max/den.
// Near-one-hot softmax -> ballot-compressed accumulate loop.
__global__ __launch_bounds__(256) void node_fused(
    const float* __restrict__ h, const double* __restrict__ a_src,
    const double* __restrict__ a_dst, const float* __restrict__ edges,
    const int* __restrict__ srt_sender, const int* __restrict__ offsets,
    const float* __restrict__ attn_W, const float* __restrict__ attn_b,
    const double* __restrict__ Ssum, float* __restrict__ out) {
    int node = blockIdx.x * 4 + (threadIdx.x >> 6);
    int lane = threadIdx.x & 63;
    if (node >= N_NODES) return;
    int hd = lane >> 4, q = lane & 15;
    int start = offsets[node], end = offsets[node + 1];
    long long obase = (long long)node * HID + lane;
    if (start >= end) { out[obase] = 0.f; return; }

    double S = 4.0 * Ssum[0];                       // sent_e tiled over heads
    double w    = (double)attn_W[hd * AW_COLS + 2 * OUT_DIM];
    double bb   = (double)attn_b[hd];
    double adst = a_dst[node * N_HEADS + hd];
    float m_run = -INFINITY;
    float den = 0.f, acc = 0.f;

    for (int cbase = start; cbase < end; cbase += 64) {
        int cd = end - cbase; if (cd > 64) cd = 64;
        float y[4], ev[4];
        #pragma unroll
        for (int j = 0; j < 4; ++j) {
            int ei = q + 16 * j;
            y[j] = -INFINITY;
            if (ei < cd) {
                int s = srt_sender[cbase + ei];
                double se = (double)edges[s];
                double as = a_src[(long long)s * N_HEADS + hd];
                double yy = as + adst + se * w + bb;
                yy = yy > 0.0 ? yy : 0.01 * yy;     // leaky (fp64, then round)
                y[j] = (float)yy;
            }
        }
        // per-head (16-lane segment) chunk max
        float mv = fmaxf(fmaxf(y[0], y[1]), fmaxf(y[2], y[3]));
        #pragma unroll
        for (int k = 1; k <= 8; k <<= 1)
            mv = fmaxf(mv, __shfl_xor(mv, k, 64));
        float mn = fmaxf(m_run, mv);
        float sc = (m_run == -INFINITY) ? 0.f
                 : __expf((float)(S * ((double)m_run - (double)mn)));
        den *= sc; acc *= sc; m_run = mn;
        // ev per slot (fp64 arg, fp32 exp) + segmented den sum
        float dsum = 0.f;
        #pragma unroll
        for (int j = 0; j < 4; ++j) {
            ev[j] = (y[j] == -INFINITY) ? 0.f
                  : __expf((float)(S * ((double)y[j] - (double)m_run)));
            dsum += ev[j];
        }
        #pragma unroll
        for (int k = 1; k <= 8; k <<= 1)
            dsum += __shfl_xor(dsum, k, 64);
        den += dsum;
        // accumulate only surviving edges (exact skip of ev==0)
        #pragma unroll
        for (int j = 0; j < 4; ++j) {
            unsigned long long mk = __ballot(ev[j] != 0.f);
            unsigned um = (unsigned)((mk | (mk >> 16) | (mk >> 32) | (mk >> 48)) & 0xFFFFull);
            while (um) {
                int qq = __builtin_ctz(um);
                um &= um - 1;
                float evv = __shfl(ev[j], (lane & 48) | qq, 64);  // own head's ev
                int sj = srt_sender[cbase + 16 * j + qq];         // uniform -> scalar
                if (evv != 0.f)
                    acc = fmaf(evv, h[(long long)sj * HID + lane], acc);
            }
        }
    }
    float r = (den > 0.f) ? acc / den : 0.f;
    out[obase] = r > 0.f ? r : 0.01f * r;
}

static inline char* ws_take(char*& p, size_t bytes) {
    char* cur = p;
    p += (bytes + 255) & ~(size_t)255;   // keep every buffer 256B-aligned
    return cur;
}

extern "C" void kernel_launch(void* const* d_in, const int* in_sizes, int n_in,
                              void* d_out, int out_size, void* d_ws, size_t ws_size,
                              hipStream_t stream) {
    const float* nodes     = (const float*)d_in[0];
    const float* edges     = (const float*)d_in[1];
    const int*   senders   = (const int*)d_in[2];
    const int*   receivers = (const int*)d_in[3];
    const float* W         = (const float*)d_in[4];
    const float* b         = (const float*)d_in[5];
    const float* attn_W    = (const float*)d_in[6];
    const float* attn_b    = (const float*)d_in[7];
    float* out = (float*)d_out;

    char* p = (char*)d_ws;
    float*  h          = (float*)ws_take(p, sizeof(float) * N_NODES * HID);
    double* a_src      = (double*)ws_take(p, sizeof(double) * N_NODES * N_HEADS);
    double* a_dst      = (double*)ws_take(p, sizeof(double) * N_NODES * N_HEADS);
    int*    counts     = (int*)ws_take(p, sizeof(int) * N_NODES);
    int*    offsets    = (int*)ws_take(p, sizeof(int) * (N_NODES + 1));
    int*    cursor     = (int*)ws_take(p, sizeof(int) * N_NODES);
    int*    partials   = (int*)ws_take(p, sizeof(int) * NBLK);
    int*    srt_sender = (int*)ws_take(p, sizeof(int) * (size_t)N_EDGES);
    double* Ssum       = (double*)ws_take(p, sizeof(double));

    hipMemsetAsync(counts, 0, sizeof(int) * N_NODES, stream);
    hipMemsetAsync(Ssum, 0, sizeof(double), stream);

    gemm_h<<<(N_NODES + GN - 1) / GN, 256, 0, stream>>>(nodes, W, b, attn_W, h, a_src, a_dst);
    hist<<<HBLK, 256, 0, stream>>>(senders, receivers, edges, counts, Ssum);
    partial_sums<<<NBLK, 256, 0, stream>>>(counts, partials);
    scan_partials<<<1, 256, 0, stream>>>(partials);
    scan_final<<<NBLK, 256, 0, stream>>>(counts, partials, offsets, cursor);
    fill_srt<<<FBLK, 256, 0, stream>>>(senders, receivers, cursor, srt_sender);
    node_fused<<<(N_NODES + 3) / 4, 256, 0, stream>>>(
        h, a_src, a_dst, edges, srt_sender, offsets, attn_W, attn_b, Ssum, out);
}

// Round 13
// 225.909 us; speedup vs baseline: 1.3761x; 1.1922x over previous
//
#include <hip/hip_runtime.h>
#include <math.h>

#define N_NODES 50000
#define N_EDGES 800000
#define IN_DIM 128
#define OUT_DIM 16
#define N_HEADS 4
#define HID 64            // N_HEADS*OUT_DIM
#define AW_COLS 33        // 2*OUT_DIM+1
#define NBLK ((N_NODES + 255) / 256)   // 196
#define GN 32             // nodes per block (gemm)
#define GW 8              // nodes per wave  (gemm)
#define HE 16             // edges per thread (hist)
#define HBLK ((N_EDGES + 256 * HE - 1) / (256 * HE))   // 196
#define FE 4              // edges per thread (fill_srt)
#define FBLK ((N_EDGES + 256 * FE - 1) / (256 * FE))   // 782

// h = nodes @ W.T + b (fp64 accumulate, bit-identical op order to R6/R9/R11)
// + fused alphas epilogue. Block = 256 = 4 waves; wave = 8 nodes, lane = out elem.
// NOTE (R7/R8): v_mfma_f64_16x16x4_f64 gave deterministic wrong h — shelved.
// NOTE (R10): threadIdx-derived addresses never take the s_load path.
__global__ __launch_bounds__(256) void gemm_h(const float* __restrict__ nodes,
                                              const float* __restrict__ W,
                                              const float* __restrict__ b,
                                              const float* __restrict__ attn_W,
                                              float* __restrict__ h,
                                              double* __restrict__ a_src,
                                              double* __restrict__ a_dst) {
    __shared__ float sW[HID * IN_DIM];     // 32 KB, rotated-quad layout
    __shared__ float sN[GN * IN_DIM];      // 16 KB
    int t = threadIdx.x;
    for (int i4 = t; i4 < HID * IN_DIM / 4; i4 += 256) {
        int o = i4 >> 5, kq = i4 & 31;
        float4 v = ((const float4*)W)[i4];
        *(float4*)&sW[o * IN_DIM + (((kq + o) & 31) << 2)] = v;
    }
    int node0 = blockIdx.x * GN;
    for (int i4 = t; i4 < GN * IN_DIM / 4; i4 += 256) {
        int ln = i4 >> 5;
        int n = node0 + ln;
        float4 v = (n < N_NODES) ? ((const float4*)nodes)[(long long)n * (IN_DIM / 4) + (i4 & 31)]
                                 : make_float4(0.f, 0.f, 0.f, 0.f);
        *(float4*)&sN[i4 << 2] = v;
    }
    __syncthreads();
    int w = t >> 6, o = t & 63;
    double acc[GW];
    #pragma unroll
    for (int j = 0; j < GW; ++j) acc[j] = (double)b[o];
    const float* wrow = &sW[o * IN_DIM];
    const float* nbase = &sN[(w * GW) * IN_DIM];
    for (int kq = 0; kq < 32; ++kq) {
        float4 wv = *(const float4*)&wrow[((kq + o) & 31) << 2];   // rotated, spread banks
        double wx = (double)wv.x, wy = (double)wv.y;
        double wz = (double)wv.z, ww = (double)wv.w;
        #pragma unroll
        for (int j = 0; j < GW; ++j) {
            float4 nv = *(const float4*)&nbase[j * IN_DIM + (kq << 2)];  // broadcast
            acc[j] += wx * (double)nv.x;
            acc[j] += wy * (double)nv.y;
            acc[j] += wz * (double)nv.z;
            acc[j] += ww * (double)nv.w;
        }
    }
    int hd = o >> 4, d = o & 15;
    double aw0 = (double)attn_W[hd * AW_COLS + d];
    double aw1 = (double)attn_W[hd * AW_COLS + OUT_DIM + d];
    #pragma unroll
    for (int j = 0; j < GW; ++j) {
        int n = node0 + w * GW + j;          // wave-uniform validity
        if (n >= N_NODES) break;
        float hf = (float)acc[j];
        h[(long long)n * HID + o] = hf;
        double c0 = (double)hf * aw0;
        double c1 = (double)hf * aw1;
        #pragma unroll
        for (int k = 1; k <= 8; k <<= 1) {
            c0 += __shfl_xor(c0, k, 64);
            c1 += __shfl_xor(c1, k, 64);
        }
        if (d == 0) {
            a_src[n * N_HEADS + hd] = c0;
            a_dst[n * N_HEADS + hd] = c1;
        }
    }
}

// Receiver histogram + Ssum + per-edge rank. The counts atomicAdd's RETURN VALUE
// is the edge's rank among its receiver's edges (R12 discarded it, then re-derived
// it with a second atomic pass in fill_srt — the 60 us atomic->store chain).
__global__ __launch_bounds__(256) void hist(const int* __restrict__ senders,
                                            const int* __restrict__ receivers,
                                            const float* __restrict__ edges,
                                            int* __restrict__ counts,
                                            int* __restrict__ rel,
                                            double* __restrict__ Ssum) {
    __shared__ double red[256];
    int t = threadIdx.x;
    int base = blockIdx.x * 256 * HE + t;
    double sp = 0.0;
    #pragma unroll
    for (int j = 0; j < HE; ++j) {
        int e = base + j * 256;
        if (e < N_EDGES) {
            rel[e] = atomicAdd(&counts[receivers[e]], 1);   // rank 0..deg-1
            sp += (double)edges[senders[e]];
        }
    }
    red[t] = sp;
    __syncthreads();
    for (int off = 128; off > 0; off >>= 1) {
        if (t < off) red[t] += red[t + off];
        __syncthreads();
    }
    if (t == 0) atomicAdd(Ssum, red[0]);
}

// ---- 3-phase multi-block exclusive scan of counts -> offsets ----
__global__ __launch_bounds__(256) void partial_sums(const int* __restrict__ counts,
                                                    int* __restrict__ partials) {
    __shared__ int red[256];
    int t = threadIdx.x;
    int i = blockIdx.x * 256 + t;
    red[t] = (i < N_NODES) ? counts[i] : 0;
    __syncthreads();
    for (int off = 128; off > 0; off >>= 1) {
        if (t < off) red[t] += red[t + off];
        __syncthreads();
    }
    if (t == 0) partials[blockIdx.x] = red[0];
}

__global__ __launch_bounds__(256) void scan_partials(int* __restrict__ partials) {
    __shared__ int s[256];
    int t = threadIdx.x;
    int v = (t < NBLK) ? partials[t] : 0;
    s[t] = v;
    __syncthreads();
    for (int off = 1; off < 256; off <<= 1) {
        int u = (t >= off) ? s[t - off] : 0;
        __syncthreads();
        s[t] += u;
        __syncthreads();
    }
    if (t < NBLK) partials[t] = s[t] - v;   // exclusive block offsets
}

__global__ __launch_bounds__(256) void scan_final(const int* __restrict__ counts,
                                                  const int* __restrict__ partials,
                                                  int* __restrict__ offsets) {
    __shared__ int s[256];
    int t = threadIdx.x;
    int i = blockIdx.x * 256 + t;
    int c = (i < N_NODES) ? counts[i] : 0;
    s[t] = c;
    __syncthreads();
    for (int off = 1; off < 256; off <<= 1) {
        int u = (t >= off) ? s[t - off] : 0;
        __syncthreads();
        s[t] += u;
        __syncthreads();
    }
    if (i < N_NODES) offsets[i] = partials[blockIdx.x] + s[t] - c;
    if (i == 0) offsets[N_NODES] = N_EDGES;
}

// Atomic-free scatter: pos = offsets[receiver] + rank-from-hist. Three coalesced
// loads + one L2-resident gather + one fire-and-forget scattered store.
__global__ __launch_bounds__(256) void fill_srt(const int* __restrict__ senders,
                                                const int* __restrict__ receivers,
                                                const int* __restrict__ rel,
                                                const int* __restrict__ offsets,
                                                int* __restrict__ srt_sender) {
    int base = blockIdx.x * 256 * FE + threadIdx.x;
    #pragma unroll
    for (int j = 0; j < FE; ++j) {
        int e = base + j * 256;
        if (e < N_EDGES)
            srt_sender[offsets[receivers[e]] + rel[e]] = senders[e];
    }
}

// One wave per node. Lane = (head hd=lane>>4, slot q=lane&15); lane evaluates
// edges q+16j for ITS head only. Segmented 16-lane reductions for max/den.
// Near-one-hot softmax -> ballot-compressed accumulate loop.
__global__ __launch_bounds__(256) void node_fused(
    const float* __restrict__ h, const double* __restrict__ a_src,
    const double* __restrict__ a_dst, const float* __restrict__ edges,
    const int* __restrict__ srt_sender, const int* __restrict__ offsets,
    const float* __restrict__ attn_W, const float* __restrict__ attn_b,
    const double* __restrict__ Ssum, float* __restrict__ out) {
    int node = blockIdx.x * 4 + (threadIdx.x >> 6);
    int lane = threadIdx.x & 63;
    if (node >= N_NODES) return;
    int hd = lane >> 4, q = lane & 15;
    int start = offsets[node], end = offsets[node + 1];
    long long obase = (long long)node * HID + lane;
    if (start >= end) { out[obase] = 0.f; return; }

    double S = 4.0 * Ssum[0];                       // sent_e tiled over heads
    double w    = (double)attn_W[hd * AW_COLS + 2 * OUT_DIM];
    double bb   = (double)attn_b[hd];
    double adst = a_dst[node * N_HEADS + hd];
    float m_run = -INFINITY;
    float den = 0.f, acc = 0.f;

    for (int cbase = start; cbase < end; cbase += 64) {
        int cd = end - cbase; if (cd > 64) cd = 64;
        float y[4], ev[4];
        #pragma unroll
        for (int j = 0; j < 4; ++j) {
            int ei = q + 16 * j;
            y[j] = -INFINITY;
            if (ei < cd) {
                int s = srt_sender[cbase + ei];
                double se = (double)edges[s];
                double as = a_src[(long long)s * N_HEADS + hd];
                double yy = as + adst + se * w + bb;
                yy = yy > 0.0 ? yy : 0.01 * yy;     // leaky (fp64, then round)
                y[j] = (float)yy;
            }
        }
        // per-head (16-lane segment) chunk max
        float mv = fmaxf(fmaxf(y[0], y[1]), fmaxf(y[2], y[3]));
        #pragma unroll
        for (int k = 1; k <= 8; k <<= 1)
            mv = fmaxf(mv, __shfl_xor(mv, k, 64));
        float mn = fmaxf(m_run, mv);
        float sc = (m_run == -INFINITY) ? 0.f
                 : __expf((float)(S * ((double)m_run - (double)mn)));
        den *= sc; acc *= sc; m_run = mn;
        // ev per slot (fp64 arg, fp32 exp) + segmented den sum
        float dsum = 0.f;
        #pragma unroll
        for (int j = 0; j < 4; ++j) {
            ev[j] = (y[j] == -INFINITY) ? 0.f
                  : __expf((float)(S * ((double)y[j] - (double)m_run)));
            dsum += ev[j];
        }
        #pragma unroll
        for (int k = 1; k <= 8; k <<= 1)
            dsum += __shfl_xor(dsum, k, 64);
        den += dsum;
        // accumulate only surviving edges (exact skip of ev==0)
        #pragma unroll
        for (int j = 0; j < 4; ++j) {
            unsigned long long mk = __ballot(ev[j] != 0.f);
            unsigned um = (unsigned)((mk | (mk >> 16) | (mk >> 32) | (mk >> 48)) & 0xFFFFull);
            while (um) {
                int qq = __builtin_ctz(um);
                um &= um - 1;
                float evv = __shfl(ev[j], (lane & 48) | qq, 64);  // own head's ev
                int sj = srt_sender[cbase + 16 * j + qq];         // uniform -> scalar
                if (evv != 0.f)
                    acc = fmaf(evv, h[(long long)sj * HID + lane], acc);
            }
        }
    }
    float r = (den > 0.f) ? acc / den : 0.f;
    out[obase] = r > 0.f ? r : 0.01f * r;
}

static inline char* ws_take(char*& p, size_t bytes) {
    char* cur = p;
    p += (bytes + 255) & ~(size_t)255;   // keep every buffer 256B-aligned
    return cur;
}

extern "C" void kernel_launch(void* const* d_in, const int* in_sizes, int n_in,
                              void* d_out, int out_size, void* d_ws, size_t ws_size,
                              hipStream_t stream) {
    const float* nodes     = (const float*)d_in[0];
    const float* edges     = (const float*)d_in[1];
    const int*   senders   = (const int*)d_in[2];
    const int*   receivers = (const int*)d_in[3];
    const float* W         = (const float*)d_in[4];
    const float* b         = (const float*)d_in[5];
    const float* attn_W    = (const float*)d_in[6];
    const float* attn_b    = (const float*)d_in[7];
    float* out = (float*)d_out;

    char* p = (char*)d_ws;
    float*  h          = (float*)ws_take(p, sizeof(float) * N_NODES * HID);
    double* a_src      = (double*)ws_take(p, sizeof(double) * N_NODES * N_HEADS);
    double* a_dst      = (double*)ws_take(p, sizeof(double) * N_NODES * N_HEADS);
    int*    counts     = (int*)ws_take(p, sizeof(int) * N_NODES);
    int*    offsets    = (int*)ws_take(p, sizeof(int) * (N_NODES + 1));
    int*    rel        = (int*)ws_take(p, sizeof(int) * (size_t)N_EDGES);
    int*    partials   = (int*)ws_take(p, sizeof(int) * NBLK);
    int*    srt_sender = (int*)ws_take(p, sizeof(int) * (size_t)N_EDGES);
    double* Ssum       = (double*)ws_take(p, sizeof(double));

    hipMemsetAsync(counts, 0, sizeof(int) * N_NODES, stream);
    hipMemsetAsync(Ssum, 0, sizeof(double), stream);

    gemm_h<<<(N_NODES + GN - 1) / GN, 256, 0, stream>>>(nodes, W, b, attn_W, h, a_src, a_dst);
    hist<<<HBLK, 256, 0, stream>>>(senders, receivers, edges, counts, rel, Ssum);
    partial_sums<<<NBLK, 256, 0, stream>>>(counts, partials);
    scan_partials<<<1, 256, 0, stream>>>(partials);
    scan_final<<<NBLK, 256, 0, stream>>>(counts, partials, offsets);
    fill_srt<<<FBLK, 256, 0, stream>>>(senders, receivers, rel, offsets, srt_sender);
    node_fused<<<(N_NODES + 3) / 4, 256, 0, stream>>>(
        h, a_src, a_dst, edges, srt_sender, offsets, attn_W, attn_b, Ssum, out);
}